// Round 8
// baseline (769.584 us; speedup 1.0000x reference)
//
#include <hip/hip_runtime.h>

#define TT  1024
#define DIN 8

// sigma(x) = 1 / (1 + exp2(-x*log2e))
__device__ __forceinline__ float fsig(float x) {
    float e = __builtin_amdgcn_exp2f(-1.4426950408889634f * x);
    return __builtin_amdgcn_rcpf(1.0f + e);
}
// tanh(x) = 2*sigma(2x) - 1
__device__ __forceinline__ float ftanh_(float x) {
    float e = __builtin_amdgcn_exp2f(-2.8853900817779268f * x);
    return 2.0f * __builtin_amdgcn_rcpf(1.0f + e) - 1.0f;
}
// readlane -> wave-uniform (SGPR) value; legal as the single scalar FMA operand
__device__ __forceinline__ float bcastf(float v, int k) {
    return __uint_as_float((unsigned)__builtin_amdgcn_readlane((int)__float_as_uint(v), k));
}
// DPP permutes (compile-time ctrl). 0xB1 = quad_perm(1,0,3,2) pair swap;
// 0x00/0x55/0xAA/0xFF broadcast quad-lane 0/1/2/3 to the whole quad.
template<int CTRL>
__device__ __forceinline__ float dppf(float v) {
    return __uint_as_float((unsigned)__builtin_amdgcn_update_dpp(
        0, (int)__float_as_uint(v), CTRL, 0xF, 0xF, true));
}
// lgkm-only barrier (keep: semantics proven correct; out-stores and x loads
// stay in flight; memory clobber fences compiler motion both directions).
__device__ __forceinline__ void bar_lgkm() {
    asm volatile("s_waitcnt lgkmcnt(0)\n\ts_barrier" ::: "memory");
}
__device__ __forceinline__ void row32g(const float* __restrict__ p, float* r) {
#pragma unroll
    for (int qq = 0; qq < 8; ++qq) {
        float4 v = reinterpret_cast<const float4*>(p)[qq];
        r[4*qq]=v.x; r[4*qq+1]=v.y; r[4*qq+2]=v.z; r[4*qq+3]=v.w;
    }
}
__device__ __forceinline__ void lds32(const float* p, float* r) {
#pragma unroll
    for (int qq = 0; qq < 8; ++qq) {
        float4 v = reinterpret_cast<const float4*>(p)[qq];
        r[4*qq]=v.x; r[4*qq+1]=v.y; r[4*qq+2]=v.z; r[4*qq+3]=v.w;
    }
}

// ---- role bodies as macros (static parity, shared locals by name) ----
// L1 step (R2's verified pair layout): even lane=(i,g) rows, odd=(f,o), pair j.
#define L1STEP(X0, X1, PAR)                                                   \
    {                                                                         \
        float p0a = bq0, p0b = 0.f, p1a = bq1, p1b = 0.f;                     \
        _Pragma("unroll")                                                     \
        for (int k = 0; k < 32; k += 2) {                                     \
            p0a += wh0[k]*hs[k];   p0b += wh0[k+1]*hs[k+1];                   \
            p1a += wh1[k]*hs[k];   p1b += wh1[k+1]*hs[k+1];                   \
        }                                                                     \
        p0a += wx0[0]*X0.x; p0b += wx0[1]*X0.y;                               \
        p0a += wx0[2]*X0.z; p0b += wx0[3]*X0.w;                               \
        p0a += wx0[4]*X1.x; p0b += wx0[5]*X1.y;                               \
        p0a += wx0[6]*X1.z; p0b += wx0[7]*X1.w;                               \
        p1a += wx1[0]*X0.x; p1b += wx1[1]*X0.y;                               \
        p1a += wx1[2]*X0.z; p1b += wx1[3]*X0.w;                               \
        p1a += wx1[4]*X1.x; p1b += wx1[5]*X1.y;                               \
        p1a += wx1[6]*X1.z; p1b += wx1[7]*X1.w;                               \
        float pp0 = p0a + p0b, pp1 = p1a + p1b;                               \
        float A  = fsig(pp0);                                                 \
        float uu = q ? pp1 : (pp1 + pp1);                                     \
        float S  = fsig(uu);                                                  \
        float Bv = q ? S : (S + S - 1.0f);                                    \
        float An = dppf<0xB1>(A), Bn = dppf<0xB1>(Bv);                        \
        float si = q ? An : A,  sf = q ? A  : An;                             \
        float tg = q ? Bn : Bv, so = q ? Bv : Bn;                             \
        c1 = sf * c1 + si * tg;                                               \
        float h1v = so * ftanh_(c1);                                          \
        if (!q) hb1[elem][PAR][j] = h1v;                                      \
        _Pragma("unroll")                                                     \
        for (int k = 0; k < 32; ++k) hs[k] = bcastf(h1v, 2*k);                \
    }

// L2 step for target parity PT: h1(tau) from hb1[PT] (strided+readlane->SGPR),
// h2(tau-1) from hb2[PT^1] (uniform b128), publish h2(tau) -> hb2[PT].
#define L2STEP(PT)                                                            \
    {                                                                         \
        float h1l = hb1[elem][PT][l & 31];                                    \
        float h2r_[32];                                                       \
        lds32(&hb2[elem][(PT)^1][0], h2r_);                                   \
        float h1s_[32];                                                       \
        _Pragma("unroll")                                                     \
        for (int k = 0; k < 32; ++k) h1s_[k] = bcastf(h1l, k);                \
        float a0 = bq, a1 = 0.f, a2 = 0.f, a3 = 0.f;                          \
        _Pragma("unroll")                                                     \
        for (int k = 0; k < 32; k += 4) {                                     \
            a0 += w2[k]  *h1s_[k];   a1 += w2[k+1]*h1s_[k+1];                 \
            a2 += w2[k+2]*h1s_[k+2]; a3 += w2[k+3]*h1s_[k+3];                 \
        }                                                                     \
        _Pragma("unroll")                                                     \
        for (int k = 0; k < 32; k += 4) {                                     \
            a0 += u2[k]  *h2r_[k];   a1 += u2[k+1]*h2r_[k+1];                 \
            a2 += u2[k+2]*h2r_[k+2]; a3 += u2[k+3]*h2r_[k+3];                 \
        }                                                                     \
        float gg = (a0 + a1) + (a2 + a3);                                     \
        float uu = isg ? (gg + gg) : gg;                                      \
        float S  = fsig(uu);                                                  \
        float av = isg ? (S + S - 1.0f) : S;                                  \
        float siq = dppf<0x00>(av);                                           \
        float sfq = dppf<0x55>(av);                                           \
        float tgq = dppf<0xAA>(av);                                           \
        float soq = dppf<0xFF>(av);                                           \
        c2 = sfq * c2 + siq * tgq;                                            \
        float h2v = soq * ftanh_(c2);                                         \
        if (g == 0) hb2[elem][PT][u] = h2v;                                   \
    }

// out step for timestep TAU (parity PT = TAU&1): read h2(TAU) from hb2[PT]
#define OUTSTEP(TAU, PT)                                                      \
    {                                                                         \
        float h2r_[32];                                                       \
        lds32(&hb2[elem][PT][0], h2r_);                                       \
        float o0 = bo0, o1 = 0.f, po0 = bo1, po1 = 0.f;                       \
        _Pragma("unroll")                                                     \
        for (int k = 0; k < 32; k += 2) {                                     \
            o0  += wl0[k]*h2r_[k];  o1  += wl0[k+1]*h2r_[k+1];                \
            po0 += wl1[k]*h2r_[k];  po1 += wl1[k+1]*h2r_[k+1];                \
        }                                                                     \
        outb[(size_t)(TAU)*80 + c0] = o0 + o1;                                \
        if (l < 16) outb[(size_t)(TAU)*80 + 64 + l] = po0 + po1;              \
    }

// 8 waves / block = 2 batch elements x 4 role-waves (role = wv&3, elem = wv>>2).
//  role 0: whole layer 1 in one wave (2 rows/lane, 80 wts); h1 recurrence via
//          self-readlane (no LDS reads), publishes 32 floats/step.
//  roles 1-2: layer 2, 1 row/lane (64 wts); h1 via 1 strided ds_read + 32
//          readlanes (SGPR operand), h2 via 8 uniform b128; quad-DPP cell.
//  role 3: out-linear (cols l, 64+l), 2 steps behind, 8 uniform b128.
// Pipeline: iter t -> h1(t) | h2(t-1) | out(t-2). One lgkm barrier per iter.
// Separate per-role loops (equal barrier counts) keep register lifetimes
// disjoint so the allocator sees max(role) not sum(roles).
__global__ void __launch_bounds__(512, 2)
lstm_roles(const float* __restrict__ x,
           const float* __restrict__ Wih1, const float* __restrict__ Whh1,
           const float* __restrict__ bih1, const float* __restrict__ bhh1,
           const float* __restrict__ Wih2, const float* __restrict__ Whh2,
           const float* __restrict__ bih2, const float* __restrict__ bhh2,
           const float* __restrict__ Wlin, const float* __restrict__ blin,
           float* __restrict__ out)
{
    const int tid  = threadIdx.x;
    const int wv   = tid >> 6;
    const int l    = tid & 63;
    const int role = wv & 3;
    const int elem = wv >> 2;
    const int b    = blockIdx.x * 2 + elem;

    __shared__ __align__(16) float hb1[2][2][32];   // [elem][parity][unit]
    __shared__ __align__(16) float hb2[2][2][32];
    if (tid < 128)      ((float*)hb1)[tid]       = 0.f;
    else if (tid < 256) ((float*)hb2)[tid - 128] = 0.f;

    const float* __restrict__ xb = x   + (size_t)b * (TT*DIN);
    float* __restrict__ outb     = out + (size_t)b * (TT*80);

    if (role == 0) {
        // ===== layer 1 =====
        const int q = l & 1, j = l >> 1;
        const int r0 = q ? (32 + j) : j;          // i | f
        const int r1 = q ? (96 + j) : (64 + j);   // g | o
        float wx0[8], wx1[8];
#pragma unroll
        for (int k = 0; k < 8; ++k) { wx0[k] = Wih1[r0*8+k]; wx1[k] = Wih1[r1*8+k]; }
        float wh0[32], wh1[32];
        row32g(Whh1 + r0*32, wh0); row32g(Whh1 + r1*32, wh1);
        const float bq0 = bih1[r0] + bhh1[r0];
        const float bq1 = bih1[r1] + bhh1[r1];
        float hs[32];
#pragma unroll
        for (int k = 0; k < 32; ++k) hs[k] = 0.f;
        float c1 = 0.f;
        // 2-deep static x prefetch: slots A (even t), B (odd t)
        float4 xA0 = reinterpret_cast<const float4*>(xb)[0];
        float4 xA1 = reinterpret_cast<const float4*>(xb)[1];
        float4 xB0 = reinterpret_cast<const float4*>(xb)[2];
        float4 xB1 = reinterpret_cast<const float4*>(xb)[3];

        bar_lgkm();

#pragma unroll 1
        for (int tp = 0; tp < TT/2; ++tp) {
            const int te = 2*tp;
            L1STEP(xA0, xA1, 0)
            {
                const int tn = (te + 2 <= TT - 1) ? (te + 2) : 0;
                xA0 = reinterpret_cast<const float4*>(xb + tn*DIN)[0];
                xA1 = reinterpret_cast<const float4*>(xb + tn*DIN)[1];
            }
            bar_lgkm();
            L1STEP(xB0, xB1, 1)
            {
                const int tn = (te + 3 <= TT - 1) ? (te + 3) : 0;
                xB0 = reinterpret_cast<const float4*>(xb + tn*DIN)[0];
                xB1 = reinterpret_cast<const float4*>(xb + tn*DIN)[1];
            }
            bar_lgkm();
        }
        bar_lgkm();   // drain iter TT (idle)
        bar_lgkm();   // drain iter TT+1 (idle)
    } else if (role <= 2) {
        // ===== layer 2 =====
        const int g  = l & 3;                    // quad-local gate i,f,g,o
        const int u  = (role - 1)*16 + (l >> 2); // hidden unit 0..31
        const int R  = g*32 + u;
        const bool isg = (g == 2);
        float w2[32], u2[32];
        row32g(Wih2 + R*32, w2); row32g(Whh2 + R*32, u2);
        const float bq = bih2[R] + bhh2[R];
        float c2 = 0.f;

        bar_lgkm();

#pragma unroll 1
        for (int tp = 0; tp < TT/2; ++tp) {
            if (tp > 0) L2STEP(1)     // iter t=2tp: tau = t-1 (odd parity)
            bar_lgkm();
            L2STEP(0)                 // iter t=2tp+1: tau = 2tp (even parity)
            bar_lgkm();
        }
        L2STEP(1)                     // drain iter TT: tau = TT-1
        bar_lgkm();
        bar_lgkm();                   // drain iter TT+1 (idle)
    } else {
        // ===== output linear =====
        const int c0  = l;
        const int c1c = (l < 16) ? (64 + l) : 79;   // clamp: loads valid, unused
        float wl0[32], wl1[32];
        row32g(Wlin + c0*32,  wl0);
        row32g(Wlin + c1c*32, wl1);
        const float bo0 = blin[c0], bo1 = blin[c1c];

        bar_lgkm();

#pragma unroll 1
        for (int tp = 0; tp < TT/2; ++tp) {
            const int te = 2*tp;
            if (tp >= 1) OUTSTEP(te - 2, 0)   // iter t=te: tau=te-2
            bar_lgkm();
            if (tp >= 1) OUTSTEP(te - 1, 1)   // iter t=te+1: tau=te-1
            bar_lgkm();
        }
        OUTSTEP(TT - 2, 0)            // drain iter TT
        bar_lgkm();
        OUTSTEP(TT - 1, 1)            // drain iter TT+1
        bar_lgkm();
    }
}

extern "C" void kernel_launch(void* const* d_in, const int* in_sizes, int n_in,
                              void* d_out, int out_size, void* d_ws, size_t ws_size,
                              hipStream_t stream) {
    const float* x    = (const float*)d_in[0];
    const float* Wih1 = (const float*)d_in[1];
    const float* Whh1 = (const float*)d_in[2];
    const float* bih1 = (const float*)d_in[3];
    const float* bhh1 = (const float*)d_in[4];
    const float* Wih2 = (const float*)d_in[5];
    const float* Whh2 = (const float*)d_in[6];
    const float* bih2 = (const float*)d_in[7];
    const float* bhh2 = (const float*)d_in[8];
    const float* Wlin = (const float*)d_in[9];
    const float* blin = (const float*)d_in[10];

    const int B = in_sizes[0] / (TT * DIN);   // 256
    const int G = B / 2;                      // 2 batch elements per block

    hipLaunchKernelGGL(lstm_roles, dim3(G), dim3(512), 0, stream,
                       x, Wih1, Whh1, bih1, bhh1,
                       Wih2, Whh2, bih2, bhh2, Wlin, blin,
                       (float*)d_out);
}

// Round 9
// 475.907 us; speedup vs baseline: 1.6171x; 1.6171x over previous
//
#include <hip/hip_runtime.h>

#define TT  1024
#define DIN 8

// sigma(x) = 1 / (1 + exp2(-x*log2e))
__device__ __forceinline__ float fsig(float x) {
    float e = __builtin_amdgcn_exp2f(-1.4426950408889634f * x);
    return __builtin_amdgcn_rcpf(1.0f + e);
}
// tanh(x) = 2*sigma(2x) - 1
__device__ __forceinline__ float ftanh_(float x) {
    float e = __builtin_amdgcn_exp2f(-2.8853900817779268f * x);
    return 2.0f * __builtin_amdgcn_rcpf(1.0f + e) - 1.0f;
}
// DPP lane permute, compile-time ctrl. 0xB1 = quad_perm(1,0,3,2) (swap 2k<->2k+1)
// 0x114 = row_shr:4 (lane i <- i-4), 0x112 = row_shr:2, 0x102 = row_shl:2 (i <- i+2)
template<int CTRL>
__device__ __forceinline__ float dppf(float v) {
    return __uint_as_float((unsigned)__builtin_amdgcn_update_dpp(
        0, (int)__float_as_uint(v), CTRL, 0xF, 0xF, true));
}
// lgkm-only barrier: ds_writes visible + ds_reads of old parity slot complete.
// Global out-stores (never read back) and the x prefetch stay in flight.
// Single asm block: compiler cannot sink ds ops past it (memory clobber).
__device__ __forceinline__ void bar_lgkm() {
    asm volatile("s_waitcnt lgkmcnt(0)\n\ts_barrier" ::: "memory");
}

// One pipeline step with COMPILE-TIME parities P0 = t&1, PM1 = (t-1)&1.
// Identical math/sync to the round-6 kernel (442 us); only the addressing is
// cheaper: literal-offset LDS reads, scalar (SALU) running indices for the
// out-store and x-prefetch, no per-iter parity arithmetic or 64-bit muls.
#define STEP(TCUR, P0, PM1)                                                    \
  {                                                                            \
    const int tcu = (TCUR);                                                    \
    if (isL1) {                                                                \
      if (tcu < TT) {                                                          \
        const float* hin = &hb1[P0 ^ 1][part << 4];                            \
        float a0 = bias, a1 = 0.f, a2 = 0.f, a3 = 0.f;                         \
        _Pragma("unroll")                                                      \
        for (int qq = 0; qq < 4; ++qq) {                                       \
          float4 v = reinterpret_cast<const float4*>(hin)[qq];                 \
          a0 += wg[4*qq]  *v.x; a1 += wg[4*qq+1]*v.y;                          \
          a2 += wg[4*qq+2]*v.z; a3 += wg[4*qq+3]*v.w;                          \
        }                                                                      \
        a0 += wg[16]*xcur.x; a1 += wg[17]*xcur.y;                              \
        a2 += wg[18]*xcur.z; a3 += wg[19]*xcur.w;                              \
        xcur = *reinterpret_cast<const float4*>(xb + xnt + part4);             \
        xnt  = (xnt + DIN > (TT-1)*DIN) ? (TT-1)*DIN : (xnt + DIN);            \
        float sum  = (a0 + a1) + (a2 + a3);                                    \
        float full = sum + dppf<0xB1>(sum);                                    \
        float u  = isg ? (full + full) : full;                                 \
        float S  = fsig(u);                                                    \
        float av = isg ? (S + S - 1.0f) : S;                                   \
        float itg = dppf<0x114>(av) * av;                                      \
        float fv  = dppf<0x112>(av);                                           \
        c = fv * c + itg;                                                      \
        float so  = dppf<0x102>(av);                                           \
        float hv  = so * ftanh_(c);                                            \
        if ((l & 7) == 4) hb1[P0][unit] = hv;                                  \
      }                                                                        \
      if (tcu >= 2) {                                                          \
        const float* hob = &hb2[P0][part << 4];                                \
        float o0 = obias, o1 = 0.f, o2 = 0.f, o3 = 0.f;                        \
        _Pragma("unroll")                                                      \
        for (int qq = 0; qq < 4; ++qq) {                                       \
          float4 v = reinterpret_cast<const float4*>(hob)[qq];                 \
          o0 += wl[4*qq]  *v.x; o1 += wl[4*qq+1]*v.y;                          \
          o2 += wl[4*qq+2]*v.z; o3 += wl[4*qq+3]*v.w;                          \
        }                                                                      \
        float osum  = (o0 + o1) + (o2 + o3);                                   \
        float ofull = osum + dppf<0xB1>(osum);                                 \
        if (!part && l < 40) outb[t80 + ocol] = ofull;                         \
        t80 += 80;                                                             \
      }                                                                        \
    } else {                                                                   \
      if (tcu >= 1 && tcu <= TT) {                                             \
        const float* hin = part ? &hb1[P0 ^ 1][0] : &hb2[P0][0];               \
        float a0 = bias, a1 = 0.f, a2 = 0.f, a3 = 0.f;                         \
        _Pragma("unroll")                                                      \
        for (int qq = 0; qq < 8; ++qq) {                                       \
          float4 v = reinterpret_cast<const float4*>(hin)[qq];                 \
          a0 += wg2[4*qq]  *v.x; a1 += wg2[4*qq+1]*v.y;                        \
          a2 += wg2[4*qq+2]*v.z; a3 += wg2[4*qq+3]*v.w;                        \
        }                                                                      \
        float sum  = (a0 + a1) + (a2 + a3);                                    \
        float full = sum + dppf<0xB1>(sum);                                    \
        float u  = isg ? (full + full) : full;                                 \
        float S  = fsig(u);                                                    \
        float av = isg ? (S + S - 1.0f) : S;                                   \
        float itg = dppf<0x114>(av) * av;                                      \
        float fv  = dppf<0x112>(av);                                           \
        c = fv * c + itg;                                                      \
        float so  = dppf<0x102>(av);                                           \
        float hv  = so * ftanh_(c);                                            \
        if ((l & 7) == 4) hb2[P0 ^ 1][unit] = hv;                              \
      }                                                                        \
    }                                                                          \
    bar_lgkm();                                                                \
  }

// 8 waves / batch element (block=512), layer-pipelined, 2 lanes per gate row.
// Lane l: ul=l>>3 (unit-local 0..7), g=(l>>1)&3 (i,f,g,o), part=l&1.
// Waves 0-3: layer 1 (16 h-wts + 4 x-wts per lane) + out-linear (16 wts,
//            col = wu*20 + l>>1, lanes<40), out runs 2 steps behind.
// Waves 4-7: layer 2 (32 wts: part0 = Whh2 row (h2 input), part1 = Wih2 (h1)).
// Half-sums combined via DPP quad_perm; cell update via DPP row_shr4/shr2/shl2
// onto the g-lanes (l&7 in {4,5}); lane l&7==4 publishes h to LDS.
// Pipeline at iter t: L1 -> h1(t); L2 -> h2(t-1); out(t-2). One barrier/iter.
__global__ void __launch_bounds__(512, 2)
lstm_pipe9(const float* __restrict__ x,
           const float* __restrict__ Wih1, const float* __restrict__ Whh1,
           const float* __restrict__ bih1, const float* __restrict__ bhh1,
           const float* __restrict__ Wih2, const float* __restrict__ Whh2,
           const float* __restrict__ bih2, const float* __restrict__ bhh2,
           const float* __restrict__ Wlin, const float* __restrict__ blin,
           float* __restrict__ out)
{
    const int tid  = threadIdx.x;
    const int wv   = tid >> 6;         // wave 0..7
    const int l    = tid & 63;
    const int part = l & 1;
    const int part4 = part * 4;
    const int g    = (l >> 1) & 3;     // 0=i 1=f 2=g 3=o
    const int ul   = l >> 3;           // unit-local 0..7
    const int b    = blockIdx.x;
    const bool isL1 = (wv < 4);
    const int  wu   = isL1 ? wv : (wv - 4);
    const int  unit = wu*8 + ul;       // hidden unit 0..31
    const int  R    = g*32 + unit;     // gate row 0..127
    const bool isg  = (g == 2);

    __shared__ float hb1[2][32];       // h1 by parity
    __shared__ float hb2[2][32];       // h2 by parity
    if (tid < 64)       ((float*)hb1)[tid]      = 0.f;
    else if (tid < 128) ((float*)hb2)[tid - 64] = 0.f;

    // ---- per-lane weights ----
    float wg[20];          // L1: [0:16]=Whh1 half, [16:20]=Wih1 quarter
    float wg2[32];         // L2: full 32 input wts
    float wl[16];          // L1: out-linear half column
    float bias = 0.f, obias = 0.f;
    int ocol = 0;

    if (isL1) {
        const float* wsrc = Whh1 + R*32 + part*16;
#pragma unroll
        for (int qq = 0; qq < 4; ++qq) {
            float4 v = reinterpret_cast<const float4*>(wsrc)[qq];
            wg[4*qq]=v.x; wg[4*qq+1]=v.y; wg[4*qq+2]=v.z; wg[4*qq+3]=v.w;
        }
        float4 xv = *reinterpret_cast<const float4*>(Wih1 + R*DIN + part4);
        wg[16]=xv.x; wg[17]=xv.y; wg[18]=xv.z; wg[19]=xv.w;
        if (!part) bias = bih1[R] + bhh1[R];
        ocol = wu*20 + (l >> 1);
        const int oc = (l < 40) ? ocol : 79;       // clamp: loads valid, unused
        const float* osrc = Wlin + oc*32 + part*16;
#pragma unroll
        for (int qq = 0; qq < 4; ++qq) {
            float4 v = reinterpret_cast<const float4*>(osrc)[qq];
            wl[4*qq]=v.x; wl[4*qq+1]=v.y; wl[4*qq+2]=v.z; wl[4*qq+3]=v.w;
        }
        if (!part) obias = blin[oc];
    } else {
        const float* wsrc = part ? (Wih2 + R*32) : (Whh2 + R*32);
#pragma unroll
        for (int qq = 0; qq < 8; ++qq) {
            float4 v = reinterpret_cast<const float4*>(wsrc)[qq];
            wg2[4*qq]=v.x; wg2[4*qq+1]=v.y; wg2[4*qq+2]=v.z; wg2[4*qq+3]=v.w;
        }
        if (!part) bias = bih2[R] + bhh2[R];
    }

    float c = 0.f;   // valid on lanes l&7 in {4,5}; bounded garbage elsewhere

    const float* __restrict__ xb = x   + (size_t)b * (TT*DIN);
    float* __restrict__ outb     = out + (size_t)b * (TT*80);

    int xnt = DIN;   // scalar running x offset (floats): x(t+1) prefetch target
    int t80 = 0;     // scalar running out offset (floats): 80 per emitted step

    float4 xcur;
    if (isL1) xcur = *reinterpret_cast<const float4*>(xb + part4);  // x(0) half

    bar_lgkm();   // zero-init visible

#pragma unroll 1
    for (int tp = 0; tp < TT/2; ++tp) {
        STEP(2*tp,     0, 1)
        STEP(2*tp + 1, 1, 0)
    }
    STEP(TT,     0, 1)    // drain: L2 computes h2(TT-1); out(TT-2)
    STEP(TT + 1, 1, 0)    // drain: out(TT-1)
}

extern "C" void kernel_launch(void* const* d_in, const int* in_sizes, int n_in,
                              void* d_out, int out_size, void* d_ws, size_t ws_size,
                              hipStream_t stream) {
    const float* x    = (const float*)d_in[0];
    const float* Wih1 = (const float*)d_in[1];
    const float* Whh1 = (const float*)d_in[2];
    const float* bih1 = (const float*)d_in[3];
    const float* bhh1 = (const float*)d_in[4];
    const float* Wih2 = (const float*)d_in[5];
    const float* Whh2 = (const float*)d_in[6];
    const float* bih2 = (const float*)d_in[7];
    const float* bhh2 = (const float*)d_in[8];
    const float* Wlin = (const float*)d_in[9];
    const float* blin = (const float*)d_in[10];

    const int B = in_sizes[0] / (TT * DIN);   // 256

    hipLaunchKernelGGL(lstm_pipe9, dim3(B), dim3(512), 0, stream,
                       x, Wih1, Whh1, bih1, bhh1,
                       Wih2, Whh2, bih2, bhh2, Wlin, blin,
                       (float*)d_out);
}